// Round 6
// baseline (75.743 us; speedup 1.0000x reference)
//
#include <hip/hip_runtime.h>

// ANI-1 per-species MLP, v6: cross-unit software pipelining.
// Grid = 512 persistent blocks (exactly 2/CU); block processes unit bid then
// bid+512 (unit = (atom, mol-half)). Unit i+1's aev prefetch + X staging +
// L0 B-fragment loads are issued during unit i's L1..L3 compute tail, so HBM
// streams continuously instead of bursting during L0 only.
// LDS: X dbuf (dedicated) + Y0 + Y1 = 72 KB -> 2 blocks/CU.

typedef float f32x4 __attribute__((ext_vector_type(4)));
typedef short s16x8 __attribute__((ext_vector_type(8)));

#define NMOL   128
#define NATOM  512
#define AEV    384
#define MT     64               // molecules (rows) per unit
#define XLD    136
#define Y0LD   168
#define Y1LD   136
#define Y2LD   104

// Wp element offsets (bf16 units)
#define PL0    61440            // 160*384
#define PL1    20480            // 128*160
#define PL2    12288            // 96*128
#define BASE0  0
#define BASE1  245760           // 4*PL0
#define BASE2  327680           // BASE1 + 4*PL1
#define WP_BYTE_OFF 262144      // partial buffer (512*128*4) first in d_ws

__device__ __forceinline__ ushort f2bf(float f) {   // RTN-even
    uint u = __float_as_uint(f);
    return (ushort)((u + 0x7fffu + ((u >> 16) & 1u)) >> 16);
}
__device__ __forceinline__ float bf2f(ushort h) {
    return __uint_as_float(((uint)h) << 16);
}
__device__ __forceinline__ float celu_f(float v) {
    return fmaxf(v, 0.0f) + fminf(0.1f * (__expf(10.0f * v) - 1.0f), 0.0f);
}

// ---- prep: W0..W2 fp32 -> bf16 in MFMA-B-fragment order, 8 elems/thread ----
__global__ __launch_bounds__(256) void prep_kernel(
    const float* __restrict__ W0, const float* __restrict__ W1,
    const float* __restrict__ W2, ushort* __restrict__ Wp)
{
    const int idx = blockIdx.x * 256 + threadIdx.x;   // grid = 47104 (x8 elems)
    int n, k0, KS;
    size_t base;
    const float* src;
    if (idx < 30720) {                        // L0: [4][160][384], 7680 vec/species
        const int s = idx / 7680, r = idx % 7680;
        n = r / 48; k0 = (r % 48) * 8; KS = 12;
        src = W0 + (size_t)idx * 8;
        base = BASE0 + (size_t)s * PL0;
    } else if (idx < 40960) {                 // L1: [4][128][160], 2560 vec/species
        const int i2 = idx - 30720;
        const int s = i2 / 2560, r = i2 % 2560;
        n = r / 20; k0 = (r % 20) * 8; KS = 5;
        src = W1 + (size_t)i2 * 8;
        base = BASE1 + (size_t)s * PL1;
    } else {                                  // L2: [4][96][128], 1536 vec/species
        const int i2 = idx - 40960;
        const int s = i2 / 1536, r = i2 % 1536;
        n = r / 16; k0 = (r % 16) * 8; KS = 4;
        src = W2 + (size_t)i2 * 8;
        base = BASE2 + (size_t)s * PL2;
    }
    const float4 v0 = *(const float4*)(src);
    const float4 v1 = *(const float4*)(src + 4);
    // 8 consecutive k for fixed n land in 8 consecutive frag slots
    const size_t fo = (size_t)((((n >> 4) * KS + (k0 >> 5)) * 64
                                + ((k0 & 31) >> 3) * 16 + (n & 15)) * 8);
    uint4 w;
    w.x = (uint)f2bf(v0.x) | ((uint)f2bf(v0.y) << 16);
    w.y = (uint)f2bf(v0.z) | ((uint)f2bf(v0.w) << 16);
    w.z = (uint)f2bf(v1.x) | ((uint)f2bf(v1.y) << 16);
    w.w = (uint)f2bf(v1.z) | ((uint)f2bf(v1.w) << 16);
    *(uint4*)(Wp + base + fo) = w;
}

__global__ __launch_bounds__(512, 4) void ani_mfma_kernel(
    const float* __restrict__ aev, const int* __restrict__ species,
    const ushort* __restrict__ Wp,
    const float* __restrict__ b0, const float* __restrict__ b1,
    const float* __restrict__ b2,
    const float* __restrict__ W3, const float* __restrict__ b3,
    float* __restrict__ partial)
{
    __shared__ __align__(16) ushort xbuf[2 * MT * XLD];   // 34816 B: X dbuf (dedicated)
    __shared__ __align__(16) ushort y0buf[MT * Y0LD];     // 21504 B: Y0 -> Y2
    __shared__ __align__(16) ushort y1buf[MT * Y1LD];     // 17408 B: Y1 -> red

    const int bid  = blockIdx.x;
    int a          = bid >> 1;
    const int half = bid & 1;
    const int tid  = threadIdx.x;
    const int lane = tid & 63;
    const int wid  = tid >> 6;
    const int mgrp = wid >> 2;          // 0..1
    const int ngrp = wid & 3;           // 0..3
    const bool has3 = (ngrp < 2);       // third N-frag (L0 nf=ngrp+8<10; L2 nf=ngrp+4<6)

    const int mol0 = tid >> 5;          // 0..15
    const int c4   = tid & 31;
    const size_t PSTR = (size_t)16 * NATOM * AEV;
    const float* xp = aev + ((size_t)(half * MT + mol0) * NATOM + a) * AEV + c4 * 4;

    int s = species[a];
    const ushort* Bh0 = Wp + BASE0 + (size_t)s * PL0;
    const ushort* Bh1 = Wp + BASE1 + (size_t)s * PL1;
    const ushort* Bh2 = Wp + BASE2 + (size_t)s * PL2;
    const float* b0s = b0 + s * 160;
    const float* b1s = b1 + s * 128;
    const float* b2s = b2 + s * 96;
    const float* w3s = W3 + s * 96;
    float        bb3 = b3[s];

    ushort* X0 = xbuf;
    ushort* X1 = xbuf + MT * XLD;

    float4 rv[4];
    auto prefetch_rv = [&](int t) {
        #pragma unroll
        for (int p = 0; p < 4; ++p)
            rv[p] = *(const float4*)(xp + t * 128 + p * PSTR);
    };
    auto stage = [&](ushort* dst) {
        #pragma unroll
        for (int p = 0; p < 4; ++p) {
            uint2 ph;
            ph.x = (uint)f2bf(rv[p].x) | ((uint)f2bf(rv[p].y) << 16);
            ph.y = (uint)f2bf(rv[p].z) | ((uint)f2bf(rv[p].w) << 16);
            *(uint2*)(dst + (mol0 + 16 * p) * XLD + c4 * 4) = ph;
        }
    };

    s16x8 bl[3][4];   // L0 B frags for current tile
    auto l0_bload = [&](int tile) {
        #pragma unroll
        for (int ks = 0; ks < 4; ++ks) {
            const int gks = tile * 4 + ks;
            bl[0][ks] = *(const s16x8*)(Bh0 + ((size_t)((ngrp    ) * 12 + gks) * 64 + lane) * 8);
            bl[1][ks] = *(const s16x8*)(Bh0 + ((size_t)((ngrp + 4) * 12 + gks) * 64 + lane) * 8);
        }
        if (has3) {
            #pragma unroll
            for (int ks = 0; ks < 4; ++ks) {
                const int gks = tile * 4 + ks;
                bl[2][ks] = *(const s16x8*)(Bh0 + ((size_t)((ngrp + 8) * 12 + gks) * 64 + lane) * 8);
            }
        }
    };

    f32x4 acc[2][3];
    const f32x4 zero = {0.f, 0.f, 0.f, 0.f};

    auto l0_tile = [&](const ushort* Xb) {
        #pragma unroll
        for (int ks = 0; ks < 4; ++ks) {
            s16x8 ah[2];
            #pragma unroll
            for (int mf = 0; mf < 2; ++mf)
                ah[mf] = *(const s16x8*)(Xb + (mgrp * 32 + mf * 16 + (lane & 15)) * XLD
                                         + ks * 32 + (lane >> 4) * 8);
            #pragma unroll
            for (int mf = 0; mf < 2; ++mf) {
                acc[mf][0] = __builtin_amdgcn_mfma_f32_16x16x32_bf16(ah[mf], bl[0][ks], acc[mf][0], 0, 0, 0);
                acc[mf][1] = __builtin_amdgcn_mfma_f32_16x16x32_bf16(ah[mf], bl[1][ks], acc[mf][1], 0, 0, 0);
            }
            if (has3) {
                #pragma unroll
                for (int mf = 0; mf < 2; ++mf)
                    acc[mf][2] = __builtin_amdgcn_mfma_f32_16x16x32_bf16(ah[mf], bl[2][ks], acc[mf][2], 0, 0, 0);
            }
        }
    };

    // ---- prologue: unit0 tile0 staged, bl(0) loaded, tile1 in flight ----
    prefetch_rv(0);
    stage(X0);
    l0_bload(0);
    prefetch_rv(1);
    __syncthreads();

    for (int ui = 0; ui < 2; ++ui) {
        const bool more = (ui == 0);

        #pragma unroll
        for (int mf = 0; mf < 2; ++mf)
            #pragma unroll
            for (int t = 0; t < 3; ++t) acc[mf][t] = zero;

        // ---- L0: 3 K-tiles, dbuf pipeline ----
        l0_tile(X0);  l0_bload(1);  stage(X1);  prefetch_rv(2);
        __syncthreads();
        l0_tile(X1);  l0_bload(2);  stage(X0);
        __syncthreads();
        l0_tile(X0);

        // L1 B preload (flies during L0 epilogue + barrier)
        s16x8 b1r[2][5];
        #pragma unroll
        for (int ks = 0; ks < 5; ++ks) {
            b1r[0][ks] = *(const s16x8*)(Bh1 + ((size_t)((ngrp    ) * 5 + ks) * 64 + lane) * 8);
            b1r[1][ks] = *(const s16x8*)(Bh1 + ((size_t)((ngrp + 4) * 5 + ks) * 64 + lane) * 8);
        }

        // ---- L0 epilogue -> Y0 ----
        #pragma unroll
        for (int t = 0; t < 3; ++t) {
            if (t < 2 || has3) {
                const int n = (ngrp + 4 * t) * 16 + (lane & 15);
                const float bv = b0s[n];
                #pragma unroll
                for (int mf = 0; mf < 2; ++mf) {
                    #pragma unroll
                    for (int r = 0; r < 4; ++r) {
                        const int row = mgrp * 32 + mf * 16 + (lane >> 4) * 4 + r;
                        y0buf[row * Y0LD + n] = f2bf(celu_f(acc[mf][t][r] + bv));
                    }
                }
            }
        }
        __syncthreads();

        // next unit: aev t0 prefetch starts NOW (hides under L1..L3)
        int s2 = 0;
        if (more) {
            s2 = species[a + 256];
            xp += 256 * AEV;
            prefetch_rv(0);
        }

        // ---- L1: 160 -> 128 ----
        f32x4 acc1[2][2];
        #pragma unroll
        for (int mf = 0; mf < 2; ++mf) { acc1[mf][0] = zero; acc1[mf][1] = zero; }
        #pragma unroll
        for (int ks = 0; ks < 5; ++ks) {
            s16x8 ah[2];
            #pragma unroll
            for (int mf = 0; mf < 2; ++mf)
                ah[mf] = *(const s16x8*)(y0buf + (mgrp * 32 + mf * 16 + (lane & 15)) * Y0LD
                                         + ks * 32 + (lane >> 4) * 8);
            #pragma unroll
            for (int mf = 0; mf < 2; ++mf) {
                acc1[mf][0] = __builtin_amdgcn_mfma_f32_16x16x32_bf16(ah[mf], b1r[0][ks], acc1[mf][0], 0, 0, 0);
                acc1[mf][1] = __builtin_amdgcn_mfma_f32_16x16x32_bf16(ah[mf], b1r[1][ks], acc1[mf][1], 0, 0, 0);
            }
        }

        // L2 B preload
        s16x8 b2r[2][4];
        #pragma unroll
        for (int ks = 0; ks < 4; ++ks)
            b2r[0][ks] = *(const s16x8*)(Bh2 + ((size_t)((ngrp) * 4 + ks) * 64 + lane) * 8);
        if (has3) {
            #pragma unroll
            for (int ks = 0; ks < 4; ++ks)
                b2r[1][ks] = *(const s16x8*)(Bh2 + ((size_t)((ngrp + 4) * 4 + ks) * 64 + lane) * 8);
        }

        // ---- L1 epilogue -> Y1 ----
        #pragma unroll
        for (int t = 0; t < 2; ++t) {
            const int n = (ngrp + 4 * t) * 16 + (lane & 15);
            const float bv = b1s[n];
            #pragma unroll
            for (int mf = 0; mf < 2; ++mf) {
                #pragma unroll
                for (int r = 0; r < 4; ++r) {
                    const int row = mgrp * 32 + mf * 16 + (lane >> 4) * 4 + r;
                    y1buf[row * Y1LD + n] = f2bf(celu_f(acc1[mf][t][r] + bv));
                }
            }
        }
        __syncthreads();

        // next unit: stage t0 into X0 (X free since this unit's L0 done), t1 prefetch
        if (more) {
            stage(X0);
            prefetch_rv(1);
        }

        // ---- L2: 128 -> 96 ----
        f32x4 acc2[2][2];
        #pragma unroll
        for (int mf = 0; mf < 2; ++mf) { acc2[mf][0] = zero; acc2[mf][1] = zero; }
        #pragma unroll
        for (int ks = 0; ks < 4; ++ks) {
            s16x8 ah[2];
            #pragma unroll
            for (int mf = 0; mf < 2; ++mf)
                ah[mf] = *(const s16x8*)(y1buf + (mgrp * 32 + mf * 16 + (lane & 15)) * Y1LD
                                         + ks * 32 + (lane >> 4) * 8);
            #pragma unroll
            for (int mf = 0; mf < 2; ++mf) {
                acc2[mf][0] = __builtin_amdgcn_mfma_f32_16x16x32_bf16(ah[mf], b2r[0][ks], acc2[mf][0], 0, 0, 0);
                if (has3)
                    acc2[mf][1] = __builtin_amdgcn_mfma_f32_16x16x32_bf16(ah[mf], b2r[1][ks], acc2[mf][1], 0, 0, 0);
            }
        }

        // ---- L2 epilogue -> Y2 (y0buf region, ld 104) ----
        #pragma unroll
        for (int t = 0; t < 2; ++t) {
            if (t == 0 || has3) {
                const int n = (ngrp + 4 * t) * 16 + (lane & 15);   // < 96
                const float bv = b2s[n];
                #pragma unroll
                for (int mf = 0; mf < 2; ++mf) {
                    #pragma unroll
                    for (int r = 0; r < 4; ++r) {
                        const int row = mgrp * 32 + mf * 16 + (lane >> 4) * 4 + r;
                        y0buf[row * Y2LD + n] = f2bf(celu_f(acc2[mf][t][r] + bv));
                    }
                }
            }
        }
        __syncthreads();

        // next unit: L0 tile0 B-fragments (bl free; flies through L3 + barrier)
        if (more) {
            Bh0 = Wp + BASE0 + (size_t)s2 * PL0;
            l0_bload(0);
        }

        // ---- L3: 96 -> 1 (fp32 vector) ----
        {
            float* red = (float*)y1buf;   // Y1 dead
            const int m = tid & (MT - 1);
            const int q = tid >> 6;       // 0..7, 12 inputs each
            float accv = 0.f;
            #pragma unroll
            for (int ii = 0; ii < 12; ++ii) {
                const int i = q * 12 + ii;
                accv = fmaf(w3s[i], bf2f(y0buf[m * Y2LD + i]), accv);
            }
            red[q * MT + m] = accv;
            __syncthreads();
            if (tid < MT) {
                float sm = bb3;
                #pragma unroll
                for (int qq = 0; qq < 8; ++qq) sm += red[qq * MT + tid];
                partial[(size_t)a * NMOL + half * MT + tid] = sm;
            }
        }

        if (more) {   // rotate per-unit state
            Bh1 = Wp + BASE1 + (size_t)s2 * PL1;
            Bh2 = Wp + BASE2 + (size_t)s2 * PL2;
            b0s = b0 + s2 * 160;
            b1s = b1 + s2 * 128;
            b2s = b2 + s2 * 96;
            w3s = W3 + s2 * 96;
            bb3 = b3[s2];
            a += 256;
        }
    }
}

__global__ __launch_bounds__(256) void reduce_kernel(
    const float* __restrict__ partial, float* __restrict__ out)
{
    __shared__ float red[256];
    const int m = blockIdx.x;       // molecule
    const int t = threadIdx.x;
    float sv = partial[(size_t)t * NMOL + m] + partial[(size_t)(t + 256) * NMOL + m];
    red[t] = sv;
    __syncthreads();
    #pragma unroll
    for (int w = 128; w > 0; w >>= 1) {
        if (t < w) red[t] += red[t + w];
        __syncthreads();
    }
    if (t == 0) out[m] = red[0];
}

extern "C" void kernel_launch(void* const* d_in, const int* in_sizes, int n_in,
                              void* d_out, int out_size, void* d_ws, size_t ws_size,
                              hipStream_t stream) {
    const float* aev     = (const float*)d_in[0];
    const int*   species = (const int*)  d_in[1];
    const float* W0 = (const float*)d_in[2];
    const float* b0 = (const float*)d_in[3];
    const float* W1 = (const float*)d_in[4];
    const float* b1 = (const float*)d_in[5];
    const float* W2 = (const float*)d_in[6];
    const float* b2 = (const float*)d_in[7];
    const float* W3 = (const float*)d_in[8];
    const float* b3 = (const float*)d_in[9];
    float* out     = (float*)d_out;
    float* partial = (float*)d_ws;                               // 256 KiB
    ushort* Wp     = (ushort*)((char*)d_ws + WP_BYTE_OFF);       // ~0.75 MiB

    prep_kernel<<<184, 256, 0, stream>>>(W0, W1, W2, Wp);
    ani_mfma_kernel<<<512, 512, 0, stream>>>(aev, species, Wp,
                                             b0, b1, b2, W3, b3, partial);
    reduce_kernel<<<NMOL, 256, 0, stream>>>(partial, out);
}

// Round 7
// 54.353 us; speedup vs baseline: 1.3935x; 1.3935x over previous
//
#include <hip/hip_runtime.h>

// ANI-1 per-species MLP, v7: v5 pipeline + persistent 2-unit blocks with
// REGISTER-NEUTRAL cross-unit prefetch (v6 spilled: 80MB scratch writes from
// holding next-unit B-frags live across L3; here only rv[4] — already dead
// after L0 — carries next-unit data). Vectorized prep from v6.
// Block = 512 thr (8 waves: 2 M-grp x 4 N-grp), grid = 512 persistent.
// LDS 56.3 KB -> 2 blocks/CU. Y1/red live in X1 half; X0 staged early.

typedef float f32x4 __attribute__((ext_vector_type(4)));
typedef short s16x8 __attribute__((ext_vector_type(8)));

#define NMOL   128
#define NATOM  512
#define AEV    384
#define MT     64               // molecules (rows) per unit
#define XLD    136
#define Y0LD   168
#define Y1LD   136
#define Y2LD   104

// Wp element offsets (bf16 units)
#define PL0    61440            // 160*384
#define PL1    20480            // 128*160
#define PL2    12288            // 96*128
#define BASE0  0
#define BASE1  245760           // 4*PL0
#define BASE2  327680           // BASE1 + 4*PL1
#define WP_BYTE_OFF 262144      // partial buffer (512*128*4) first in d_ws

__device__ __forceinline__ ushort f2bf(float f) {   // RTN-even
    uint u = __float_as_uint(f);
    return (ushort)((u + 0x7fffu + ((u >> 16) & 1u)) >> 16);
}
__device__ __forceinline__ float bf2f(ushort h) {
    return __uint_as_float(((uint)h) << 16);
}
__device__ __forceinline__ float celu_f(float v) {
    return fmaxf(v, 0.0f) + fminf(0.1f * (__expf(10.0f * v) - 1.0f), 0.0f);
}

// ---- prep: W0..W2 fp32 -> bf16 in MFMA-B-fragment order, 8 elems/thread ----
__global__ __launch_bounds__(256) void prep_kernel(
    const float* __restrict__ W0, const float* __restrict__ W1,
    const float* __restrict__ W2, ushort* __restrict__ Wp)
{
    const int idx = blockIdx.x * 256 + threadIdx.x;   // grid = 47104 (x8 elems)
    int n, k0, KS;
    size_t base;
    const float* src;
    if (idx < 30720) {                        // L0: [4][160][384], 7680 vec/species
        const int s = idx / 7680, r = idx % 7680;
        n = r / 48; k0 = (r % 48) * 8; KS = 12;
        src = W0 + (size_t)idx * 8;
        base = BASE0 + (size_t)s * PL0;
    } else if (idx < 40960) {                 // L1: [4][128][160], 2560 vec/species
        const int i2 = idx - 30720;
        const int s = i2 / 2560, r = i2 % 2560;
        n = r / 20; k0 = (r % 20) * 8; KS = 5;
        src = W1 + (size_t)i2 * 8;
        base = BASE1 + (size_t)s * PL1;
    } else {                                  // L2: [4][96][128], 1536 vec/species
        const int i2 = idx - 40960;
        const int s = i2 / 1536, r = i2 % 1536;
        n = r / 16; k0 = (r % 16) * 8; KS = 4;
        src = W2 + (size_t)i2 * 8;
        base = BASE2 + (size_t)s * PL2;
    }
    const float4 v0 = *(const float4*)(src);
    const float4 v1 = *(const float4*)(src + 4);
    const size_t fo = (size_t)((((n >> 4) * KS + (k0 >> 5)) * 64
                                + ((k0 & 31) >> 3) * 16 + (n & 15)) * 8);
    uint4 w;
    w.x = (uint)f2bf(v0.x) | ((uint)f2bf(v0.y) << 16);
    w.y = (uint)f2bf(v0.z) | ((uint)f2bf(v0.w) << 16);
    w.z = (uint)f2bf(v1.x) | ((uint)f2bf(v1.y) << 16);
    w.w = (uint)f2bf(v1.z) | ((uint)f2bf(v1.w) << 16);
    *(uint4*)(Wp + base + fo) = w;
}

__global__ __launch_bounds__(512, 4) void ani_mfma_kernel(
    const float* __restrict__ aev, const int* __restrict__ species,
    const ushort* __restrict__ Wp,
    const float* __restrict__ b0, const float* __restrict__ b1,
    const float* __restrict__ b2,
    const float* __restrict__ W3, const float* __restrict__ b3,
    float* __restrict__ partial)
{
    // X0 = xbuf[0..], X1 = xbuf[MT*XLD..]. Y1 and red alias X1 (X0 is staged
    // early for the next unit, so it must stay untouched after L0).
    __shared__ __align__(16) ushort xbuf[2 * MT * XLD];   // 34816 B
    __shared__ __align__(16) ushort ybuf[MT * Y0LD];      // 21504 B: Y0 -> Y2

    const int bid  = blockIdx.x;
    int a          = bid >> 1;
    const int half = bid & 1;
    const int tid  = threadIdx.x;
    const int lane = tid & 63;
    const int wid  = tid >> 6;
    const int mgrp = wid >> 2;          // 0..1
    const int ngrp = wid & 3;           // 0..3
    const bool has3 = (ngrp < 2);       // third N-frag (L0 nf=ngrp+8<10; L2 nf=ngrp+4<6)

    const int mol0 = tid >> 5;          // 0..15
    const int c4   = tid & 31;
    const size_t PSTR = (size_t)16 * NATOM * AEV;
    const float* xp = aev + ((size_t)(half * MT + mol0) * NATOM + a) * AEV + c4 * 4;

    int s = species[a];
    const ushort* Bh0 = Wp + BASE0 + (size_t)s * PL0;
    const ushort* Bh1 = Wp + BASE1 + (size_t)s * PL1;
    const ushort* Bh2 = Wp + BASE2 + (size_t)s * PL2;
    const float* b0s = b0 + s * 160;
    const float* b1s = b1 + s * 128;
    const float* b2s = b2 + s * 96;
    const float* w3s = W3 + s * 96;
    float        bb3 = b3[s];

    ushort* X0 = xbuf;
    ushort* X1 = xbuf + MT * XLD;

    float4 rv[4];
    auto prefetch_rv = [&](int t) {
        #pragma unroll
        for (int p = 0; p < 4; ++p)
            rv[p] = *(const float4*)(xp + t * 128 + p * PSTR);
    };
    auto stage = [&](ushort* dst) {
        #pragma unroll
        for (int p = 0; p < 4; ++p) {
            uint2 ph;
            ph.x = (uint)f2bf(rv[p].x) | ((uint)f2bf(rv[p].y) << 16);
            ph.y = (uint)f2bf(rv[p].z) | ((uint)f2bf(rv[p].w) << 16);
            *(uint2*)(dst + (mol0 + 16 * p) * XLD + c4 * 4) = ph;
        }
    };

    s16x8 bl[3][4];   // L0 B frags for current tile (live ONLY inside L0)
    auto l0_bload = [&](int tile) {
        #pragma unroll
        for (int ks = 0; ks < 4; ++ks) {
            const int gks = tile * 4 + ks;
            bl[0][ks] = *(const s16x8*)(Bh0 + ((size_t)((ngrp    ) * 12 + gks) * 64 + lane) * 8);
            bl[1][ks] = *(const s16x8*)(Bh0 + ((size_t)((ngrp + 4) * 12 + gks) * 64 + lane) * 8);
        }
        if (has3) {
            #pragma unroll
            for (int ks = 0; ks < 4; ++ks) {
                const int gks = tile * 4 + ks;
                bl[2][ks] = *(const s16x8*)(Bh0 + ((size_t)((ngrp + 8) * 12 + gks) * 64 + lane) * 8);
            }
        }
    };

    f32x4 acc[2][3];
    const f32x4 zero = {0.f, 0.f, 0.f, 0.f};

    auto l0_tile = [&](const ushort* Xb) {
        #pragma unroll
        for (int ks = 0; ks < 4; ++ks) {
            s16x8 ah[2];
            #pragma unroll
            for (int mf = 0; mf < 2; ++mf)
                ah[mf] = *(const s16x8*)(Xb + (mgrp * 32 + mf * 16 + (lane & 15)) * XLD
                                         + ks * 32 + (lane >> 4) * 8);
            #pragma unroll
            for (int mf = 0; mf < 2; ++mf) {
                acc[mf][0] = __builtin_amdgcn_mfma_f32_16x16x32_bf16(ah[mf], bl[0][ks], acc[mf][0], 0, 0, 0);
                acc[mf][1] = __builtin_amdgcn_mfma_f32_16x16x32_bf16(ah[mf], bl[1][ks], acc[mf][1], 0, 0, 0);
            }
            if (has3) {
                #pragma unroll
                for (int mf = 0; mf < 2; ++mf)
                    acc[mf][2] = __builtin_amdgcn_mfma_f32_16x16x32_bf16(ah[mf], bl[2][ks], acc[mf][2], 0, 0, 0);
            }
        }
    };

    // ---- prologue: unit0 tile0 staged, tile1 in flight ----
    prefetch_rv(0);
    stage(X0);
    prefetch_rv(1);
    __syncthreads();

    for (int ui = 0; ui < 2; ++ui) {
        const bool more = (ui == 0);

        #pragma unroll
        for (int mf = 0; mf < 2; ++mf)
            #pragma unroll
            for (int t = 0; t < 3; ++t) acc[mf][t] = zero;

        // ---- L0: 3 K-tiles, dbuf pipeline (bl loaded fresh per tile) ----
        l0_bload(0);
        l0_tile(X0);  l0_bload(1);  stage(X1);  prefetch_rv(2);
        __syncthreads();
        l0_tile(X1);  l0_bload(2);  stage(X0);
        __syncthreads();
        l0_tile(X0);

        // L1 B preload (flies during L0 epilogue + barrier)
        s16x8 b1r[2][5];
        #pragma unroll
        for (int ks = 0; ks < 5; ++ks) {
            b1r[0][ks] = *(const s16x8*)(Bh1 + ((size_t)((ngrp    ) * 5 + ks) * 64 + lane) * 8);
            b1r[1][ks] = *(const s16x8*)(Bh1 + ((size_t)((ngrp + 4) * 5 + ks) * 64 + lane) * 8);
        }

        // ---- L0 epilogue -> Y0 (ybuf) ----
        #pragma unroll
        for (int t = 0; t < 3; ++t) {
            if (t < 2 || has3) {
                const int n = (ngrp + 4 * t) * 16 + (lane & 15);
                const float bv = b0s[n];
                #pragma unroll
                for (int mf = 0; mf < 2; ++mf) {
                    #pragma unroll
                    for (int r = 0; r < 4; ++r) {
                        const int row = mgrp * 32 + mf * 16 + (lane >> 4) * 4 + r;
                        ybuf[row * Y0LD + n] = f2bf(celu_f(acc[mf][t][r] + bv));
                    }
                }
            }
        }
        __syncthreads();

        // next unit: aev t0 prefetch starts NOW (rv is dead here; no extra regs)
        int s2 = 0;
        if (more) {
            s2 = species[a + 256];
            xp += 256 * AEV;
            prefetch_rv(0);
        }

        // ---- L1: 160 -> 128 (reads Y0/ybuf) ----
        f32x4 acc1[2][2];
        #pragma unroll
        for (int mf = 0; mf < 2; ++mf) { acc1[mf][0] = zero; acc1[mf][1] = zero; }
        #pragma unroll
        for (int ks = 0; ks < 5; ++ks) {
            s16x8 ah[2];
            #pragma unroll
            for (int mf = 0; mf < 2; ++mf)
                ah[mf] = *(const s16x8*)(ybuf + (mgrp * 32 + mf * 16 + (lane & 15)) * Y0LD
                                         + ks * 32 + (lane >> 4) * 8);
            #pragma unroll
            for (int mf = 0; mf < 2; ++mf) {
                acc1[mf][0] = __builtin_amdgcn_mfma_f32_16x16x32_bf16(ah[mf], b1r[0][ks], acc1[mf][0], 0, 0, 0);
                acc1[mf][1] = __builtin_amdgcn_mfma_f32_16x16x32_bf16(ah[mf], b1r[1][ks], acc1[mf][1], 0, 0, 0);
            }
        }

        // L2 B preload
        s16x8 b2r[2][4];
        #pragma unroll
        for (int ks = 0; ks < 4; ++ks)
            b2r[0][ks] = *(const s16x8*)(Bh2 + ((size_t)((ngrp) * 4 + ks) * 64 + lane) * 8);
        if (has3) {
            #pragma unroll
            for (int ks = 0; ks < 4; ++ks)
                b2r[1][ks] = *(const s16x8*)(Bh2 + ((size_t)((ngrp + 4) * 4 + ks) * 64 + lane) * 8);
        }

        // ---- L1 epilogue -> Y1 (X1 region, ld 136) ----
        #pragma unroll
        for (int t = 0; t < 2; ++t) {
            const int n = (ngrp + 4 * t) * 16 + (lane & 15);
            const float bv = b1s[n];
            #pragma unroll
            for (int mf = 0; mf < 2; ++mf) {
                #pragma unroll
                for (int r = 0; r < 4; ++r) {
                    const int row = mgrp * 32 + mf * 16 + (lane >> 4) * 4 + r;
                    X1[row * Y1LD + n] = f2bf(celu_f(acc1[mf][t][r] + bv));
                }
            }
        }
        __syncthreads();

        // next unit: stage t0 into X0 (X0 dead since tile2), prefetch t1.
        // X0 reads in next unit are separated by L2-epi + L3 barriers.
        if (more) {
            stage(X0);
            prefetch_rv(1);
        }

        // ---- L2: 128 -> 96 (reads Y1 @ X1) ----
        f32x4 acc2[2][2];
        #pragma unroll
        for (int mf = 0; mf < 2; ++mf) { acc2[mf][0] = zero; acc2[mf][1] = zero; }
        #pragma unroll
        for (int ks = 0; ks < 4; ++ks) {
            s16x8 ah[2];
            #pragma unroll
            for (int mf = 0; mf < 2; ++mf)
                ah[mf] = *(const s16x8*)(X1 + (mgrp * 32 + mf * 16 + (lane & 15)) * Y1LD
                                         + ks * 32 + (lane >> 4) * 8);
            #pragma unroll
            for (int mf = 0; mf < 2; ++mf) {
                acc2[mf][0] = __builtin_amdgcn_mfma_f32_16x16x32_bf16(ah[mf], b2r[0][ks], acc2[mf][0], 0, 0, 0);
                if (has3)
                    acc2[mf][1] = __builtin_amdgcn_mfma_f32_16x16x32_bf16(ah[mf], b2r[1][ks], acc2[mf][1], 0, 0, 0);
            }
        }

        // ---- L2 epilogue -> Y2 (ybuf, ld 104) ----
        #pragma unroll
        for (int t = 0; t < 2; ++t) {
            if (t == 0 || has3) {
                const int n = (ngrp + 4 * t) * 16 + (lane & 15);   // < 96
                const float bv = b2s[n];
                #pragma unroll
                for (int mf = 0; mf < 2; ++mf) {
                    #pragma unroll
                    for (int r = 0; r < 4; ++r) {
                        const int row = mgrp * 32 + mf * 16 + (lane >> 4) * 4 + r;
                        ybuf[row * Y2LD + n] = f2bf(celu_f(acc2[mf][t][r] + bv));
                    }
                }
            }
        }
        __syncthreads();

        // ---- L3: 96 -> 1 (fp32 vector; red in X1 region, Y1 dead) ----
        {
            float* red = (float*)X1;
            const int m = tid & (MT - 1);
            const int q = tid >> 6;       // 0..7, 12 inputs each
            float accv = 0.f;
            #pragma unroll
            for (int ii = 0; ii < 12; ++ii) {
                const int i = q * 12 + ii;
                accv = fmaf(w3s[i], bf2f(ybuf[m * Y2LD + i]), accv);
            }
            red[q * MT + m] = accv;
            __syncthreads();
            if (tid < MT) {
                float sm = bb3;
                #pragma unroll
                for (int qq = 0; qq < 8; ++qq) sm += red[qq * MT + tid];
                partial[(size_t)a * NMOL + half * MT + tid] = sm;
            }
        }
        __syncthreads();   // protect red (X1) before next unit's stage(X1)

        if (more) {        // rotate per-unit state
            Bh0 = Wp + BASE0 + (size_t)s2 * PL0;
            Bh1 = Wp + BASE1 + (size_t)s2 * PL1;
            Bh2 = Wp + BASE2 + (size_t)s2 * PL2;
            b0s = b0 + s2 * 160;
            b1s = b1 + s2 * 128;
            b2s = b2 + s2 * 96;
            w3s = W3 + s2 * 96;
            bb3 = b3[s2];
            a += 256;
        }
    }
}

__global__ __launch_bounds__(256) void reduce_kernel(
    const float* __restrict__ partial, float* __restrict__ out)
{
    __shared__ float red[256];
    const int m = blockIdx.x;       // molecule
    const int t = threadIdx.x;
    float sv = partial[(size_t)t * NMOL + m] + partial[(size_t)(t + 256) * NMOL + m];
    red[t] = sv;
    __syncthreads();
    #pragma unroll
    for (int w = 128; w > 0; w >>= 1) {
        if (t < w) red[t] += red[t + w];
        __syncthreads();
    }
    if (t == 0) out[m] = red[0];
}

extern "C" void kernel_launch(void* const* d_in, const int* in_sizes, int n_in,
                              void* d_out, int out_size, void* d_ws, size_t ws_size,
                              hipStream_t stream) {
    const float* aev     = (const float*)d_in[0];
    const int*   species = (const int*)  d_in[1];
    const float* W0 = (const float*)d_in[2];
    const float* b0 = (const float*)d_in[3];
    const float* W1 = (const float*)d_in[4];
    const float* b1 = (const float*)d_in[5];
    const float* W2 = (const float*)d_in[6];
    const float* b2 = (const float*)d_in[7];
    const float* W3 = (const float*)d_in[8];
    const float* b3 = (const float*)d_in[9];
    float* out     = (float*)d_out;
    float* partial = (float*)d_ws;                               // 256 KiB
    ushort* Wp     = (ushort*)((char*)d_ws + WP_BYTE_OFF);       // ~0.75 MiB

    prep_kernel<<<184, 256, 0, stream>>>(W0, W1, W2, Wp);
    ani_mfma_kernel<<<512, 512, 0, stream>>>(aev, species, Wp,
                                             b0, b1, b2, W3, b3, partial);
    reduce_kernel<<<NMOL, 256, 0, stream>>>(partial, out);
}

// Round 8
// 44.573 us; speedup vs baseline: 1.6993x; 1.2194x over previous
//
#include <hip/hip_runtime.h>

// ANI-1 per-species MLP, v8: M=128 per block (full molecule dim), grid=512,
// ONE round of 2 blocks/CU. vs v5: 2x MFMA per barrier/phase, half the
// B-fragment L2 traffic, half the per-unit overhead. No persistence (v7
// lesson: cross-unit reg holding spills at the compiler's 64-VGPR step).
// VGPR discipline: B-frags loaded per-ks (12 live regs, not 48/tile);
// X prefetch rv[8]=32 regs overlaps previous tile's MFMA.
// Block = 512 thr (8 waves: 2 M-grp x 4 N-grp). LDS 77.8 KB -> 2 blocks/CU.

typedef float f32x4 __attribute__((ext_vector_type(4)));
typedef short s16x8 __attribute__((ext_vector_type(8)));

#define NMOL   128
#define NATOM  512
#define AEV    384
#define XLD    136
#define Y0LD   168
#define Y1LD   136
#define Y2LD   104

// Wp element offsets (bf16 units)
#define PL0    61440            // 160*384
#define PL1    20480            // 128*160
#define PL2    12288            // 96*128
#define BASE0  0
#define BASE1  245760           // 4*PL0
#define BASE2  327680           // BASE1 + 4*PL1
#define WP_BYTE_OFF 262144      // partial buffer (512*128*4) first in d_ws

__device__ __forceinline__ ushort f2bf(float f) {   // RTN-even
    uint u = __float_as_uint(f);
    return (ushort)((u + 0x7fffu + ((u >> 16) & 1u)) >> 16);
}
__device__ __forceinline__ float bf2f(ushort h) {
    return __uint_as_float(((uint)h) << 16);
}
__device__ __forceinline__ float celu_f(float v) {
    return fmaxf(v, 0.0f) + fminf(0.1f * (__expf(10.0f * v) - 1.0f), 0.0f);
}

// ---- prep: W0..W2 fp32 -> bf16 in MFMA-B-fragment order, 8 elems/thread ----
__global__ __launch_bounds__(256) void prep_kernel(
    const float* __restrict__ W0, const float* __restrict__ W1,
    const float* __restrict__ W2, ushort* __restrict__ Wp)
{
    const int idx = blockIdx.x * 256 + threadIdx.x;   // grid = 47104 (x8 elems)
    int n, k0, KS;
    size_t base;
    const float* src;
    if (idx < 30720) {                        // L0: [4][160][384], 7680 vec/species
        const int s = idx / 7680, r = idx % 7680;
        n = r / 48; k0 = (r % 48) * 8; KS = 12;
        src = W0 + (size_t)idx * 8;
        base = BASE0 + (size_t)s * PL0;
    } else if (idx < 40960) {                 // L1: [4][128][160], 2560 vec/species
        const int i2 = idx - 30720;
        const int s = i2 / 2560, r = i2 % 2560;
        n = r / 20; k0 = (r % 20) * 8; KS = 5;
        src = W1 + (size_t)i2 * 8;
        base = BASE1 + (size_t)s * PL1;
    } else {                                  // L2: [4][96][128], 1536 vec/species
        const int i2 = idx - 40960;
        const int s = i2 / 1536, r = i2 % 1536;
        n = r / 16; k0 = (r % 16) * 8; KS = 4;
        src = W2 + (size_t)i2 * 8;
        base = BASE2 + (size_t)s * PL2;
    }
    const float4 v0 = *(const float4*)(src);
    const float4 v1 = *(const float4*)(src + 4);
    const size_t fo = (size_t)((((n >> 4) * KS + (k0 >> 5)) * 64
                                + ((k0 & 31) >> 3) * 16 + (n & 15)) * 8);
    uint4 w;
    w.x = (uint)f2bf(v0.x) | ((uint)f2bf(v0.y) << 16);
    w.y = (uint)f2bf(v0.z) | ((uint)f2bf(v0.w) << 16);
    w.z = (uint)f2bf(v1.x) | ((uint)f2bf(v1.y) << 16);
    w.w = (uint)f2bf(v1.z) | ((uint)f2bf(v1.w) << 16);
    *(uint4*)(Wp + base + fo) = w;
}

__global__ __launch_bounds__(512, 4) void ani_mfma_kernel(
    const float* __restrict__ aev, const int* __restrict__ species,
    const ushort* __restrict__ Wp,
    const float* __restrict__ b0, const float* __restrict__ b1,
    const float* __restrict__ b2,
    const float* __restrict__ W3, const float* __restrict__ b3,
    float* __restrict__ partial)
{
    __shared__ __align__(16) ushort xbuf[NMOL * XLD];   // 34816 B: X -> Y1 -> red
    __shared__ __align__(16) ushort ybuf[NMOL * Y0LD];  // 43008 B: Y0 -> Y2

    const int a    = blockIdx.x;        // atom
    const int tid  = threadIdx.x;
    const int lane = tid & 63;
    const int wid  = tid >> 6;
    const int mgrp = wid >> 2;          // 0..1 -> rows mgrp*64 .. +63
    const int ngrp = wid & 3;           // 0..3
    const bool has3 = (ngrp < 2);       // third N-frag (L0 nf=ngrp+8<10; L2 nf=ngrp+4<6)

    const int mol0 = tid >> 5;          // 0..15
    const int c4   = tid & 31;
    const size_t PSTR = (size_t)16 * NATOM * AEV;
    const float* xp = aev + ((size_t)mol0 * NATOM + a) * AEV + c4 * 4;

    const int s = species[a];
    const ushort* Bh0 = Wp + BASE0 + (size_t)s * PL0;
    const ushort* Bh1 = Wp + BASE1 + (size_t)s * PL1;
    const ushort* Bh2 = Wp + BASE2 + (size_t)s * PL2;
    const float* b0s = b0 + s * 160;
    const float* b1s = b1 + s * 128;
    const float* b2s = b2 + s * 96;
    const float* w3s = W3 + s * 96;
    const float  bb3 = b3[s];

    float4 rv[8];
    auto prefetch_rv = [&](int t) {     // [128 mol][128 k] tile -> 8 float4/thread
        #pragma unroll
        for (int p = 0; p < 8; ++p)
            rv[p] = *(const float4*)(xp + t * 128 + p * PSTR);
    };
    auto stage = [&]() {
        #pragma unroll
        for (int p = 0; p < 8; ++p) {
            uint2 ph;
            ph.x = (uint)f2bf(rv[p].x) | ((uint)f2bf(rv[p].y) << 16);
            ph.y = (uint)f2bf(rv[p].z) | ((uint)f2bf(rv[p].w) << 16);
            *(uint2*)(xbuf + (mol0 + 16 * p) * XLD + c4 * 4) = ph;
        }
    };

    f32x4 acc[4][3];
    const f32x4 zero = {0.f, 0.f, 0.f, 0.f};
    #pragma unroll
    for (int mf = 0; mf < 4; ++mf)
        #pragma unroll
        for (int t = 0; t < 3; ++t) acc[mf][t] = zero;

    // ---- L0: 384 -> 160, 3 K-tiles, single X buffer, rv prefetch overlap ----
    prefetch_rv(0);
    stage();
    __syncthreads();

    #pragma unroll
    for (int tile = 0; tile < 3; ++tile) {
        if (tile < 2) prefetch_rv(tile + 1);    // flies under this tile's MFMAs
        #pragma unroll
        for (int ks = 0; ks < 4; ++ks) {
            const int gks = tile * 4 + ks;
            // B frags per-ks: only 12 regs live (VGPR discipline)
            const s16x8 bh0 = *(const s16x8*)(Bh0 + ((size_t)((ngrp    ) * 12 + gks) * 64 + lane) * 8);
            const s16x8 bh1 = *(const s16x8*)(Bh0 + ((size_t)((ngrp + 4) * 12 + gks) * 64 + lane) * 8);
            s16x8 bh2;
            if (has3) bh2 = *(const s16x8*)(Bh0 + ((size_t)((ngrp + 8) * 12 + gks) * 64 + lane) * 8);
            s16x8 ah[4];
            #pragma unroll
            for (int mf = 0; mf < 4; ++mf)
                ah[mf] = *(const s16x8*)(xbuf + (mgrp * 64 + mf * 16 + (lane & 15)) * XLD
                                         + ks * 32 + (lane >> 4) * 8);
            #pragma unroll
            for (int mf = 0; mf < 4; ++mf) {
                acc[mf][0] = __builtin_amdgcn_mfma_f32_16x16x32_bf16(ah[mf], bh0, acc[mf][0], 0, 0, 0);
                acc[mf][1] = __builtin_amdgcn_mfma_f32_16x16x32_bf16(ah[mf], bh1, acc[mf][1], 0, 0, 0);
            }
            if (has3) {
                #pragma unroll
                for (int mf = 0; mf < 4; ++mf)
                    acc[mf][2] = __builtin_amdgcn_mfma_f32_16x16x32_bf16(ah[mf], bh2, acc[mf][2], 0, 0, 0);
            }
        }
        __syncthreads();
        if (tile < 2) {
            stage();
            __syncthreads();
        }
    }

    // L1 B preload (flies during L0 epilogue + barrier)
    s16x8 b1r[2][5];
    #pragma unroll
    for (int ks = 0; ks < 5; ++ks) {
        b1r[0][ks] = *(const s16x8*)(Bh1 + ((size_t)((ngrp    ) * 5 + ks) * 64 + lane) * 8);
        b1r[1][ks] = *(const s16x8*)(Bh1 + ((size_t)((ngrp + 4) * 5 + ks) * 64 + lane) * 8);
    }

    // ---- L0 epilogue -> Y0 (ybuf, ld 168) ----
    #pragma unroll
    for (int t = 0; t < 3; ++t) {
        if (t < 2 || has3) {
            const int n = (ngrp + 4 * t) * 16 + (lane & 15);
            const float bv = b0s[n];
            #pragma unroll
            for (int mf = 0; mf < 4; ++mf) {
                #pragma unroll
                for (int r = 0; r < 4; ++r) {
                    const int row = mgrp * 64 + mf * 16 + (lane >> 4) * 4 + r;
                    ybuf[row * Y0LD + n] = f2bf(celu_f(acc[mf][t][r] + bv));
                }
            }
        }
    }
    __syncthreads();

    // ---- L1: 160 -> 128 (A from Y0/ybuf, C -> Y1/xbuf) ----
    f32x4 acc1[4][2];
    #pragma unroll
    for (int mf = 0; mf < 4; ++mf) { acc1[mf][0] = zero; acc1[mf][1] = zero; }
    #pragma unroll
    for (int ks = 0; ks < 5; ++ks) {
        s16x8 ah[4];
        #pragma unroll
        for (int mf = 0; mf < 4; ++mf)
            ah[mf] = *(const s16x8*)(ybuf + (mgrp * 64 + mf * 16 + (lane & 15)) * Y0LD
                                     + ks * 32 + (lane >> 4) * 8);
        #pragma unroll
        for (int mf = 0; mf < 4; ++mf) {
            acc1[mf][0] = __builtin_amdgcn_mfma_f32_16x16x32_bf16(ah[mf], b1r[0][ks], acc1[mf][0], 0, 0, 0);
            acc1[mf][1] = __builtin_amdgcn_mfma_f32_16x16x32_bf16(ah[mf], b1r[1][ks], acc1[mf][1], 0, 0, 0);
        }
    }

    // L2 B preload (flies during L1 epilogue + barrier)
    s16x8 b2r[2][4];
    #pragma unroll
    for (int ks = 0; ks < 4; ++ks)
        b2r[0][ks] = *(const s16x8*)(Bh2 + ((size_t)((ngrp) * 4 + ks) * 64 + lane) * 8);
    if (has3) {
        #pragma unroll
        for (int ks = 0; ks < 4; ++ks)
            b2r[1][ks] = *(const s16x8*)(Bh2 + ((size_t)((ngrp + 4) * 4 + ks) * 64 + lane) * 8);
    }

    // ---- L1 epilogue -> Y1 (xbuf, ld 136) ----
    #pragma unroll
    for (int t = 0; t < 2; ++t) {
        const int n = (ngrp + 4 * t) * 16 + (lane & 15);
        const float bv = b1s[n];
        #pragma unroll
        for (int mf = 0; mf < 4; ++mf) {
            #pragma unroll
            for (int r = 0; r < 4; ++r) {
                const int row = mgrp * 64 + mf * 16 + (lane >> 4) * 4 + r;
                xbuf[row * Y1LD + n] = f2bf(celu_f(acc1[mf][t][r] + bv));
            }
        }
    }
    __syncthreads();

    // ---- L2: 128 -> 96 (A from Y1/xbuf, C -> Y2/ybuf ld 104) ----
    f32x4 acc2[4][2];
    #pragma unroll
    for (int mf = 0; mf < 4; ++mf) { acc2[mf][0] = zero; acc2[mf][1] = zero; }
    #pragma unroll
    for (int ks = 0; ks < 4; ++ks) {
        s16x8 ah[4];
        #pragma unroll
        for (int mf = 0; mf < 4; ++mf)
            ah[mf] = *(const s16x8*)(xbuf + (mgrp * 64 + mf * 16 + (lane & 15)) * Y1LD
                                     + ks * 32 + (lane >> 4) * 8);
        #pragma unroll
        for (int mf = 0; mf < 4; ++mf) {
            acc2[mf][0] = __builtin_amdgcn_mfma_f32_16x16x32_bf16(ah[mf], b2r[0][ks], acc2[mf][0], 0, 0, 0);
            if (has3)
                acc2[mf][1] = __builtin_amdgcn_mfma_f32_16x16x32_bf16(ah[mf], b2r[1][ks], acc2[mf][1], 0, 0, 0);
        }
    }
    __syncthreads();   // xbuf (Y1) reads done; xbuf reused for red below

    // ---- L2 epilogue -> Y2 (ybuf, ld 104) ----
    #pragma unroll
    for (int t = 0; t < 2; ++t) {
        if (t == 0 || has3) {
            const int n = (ngrp + 4 * t) * 16 + (lane & 15);   // < 96
            const float bv = b2s[n];
            #pragma unroll
            for (int mf = 0; mf < 4; ++mf) {
                #pragma unroll
                for (int r = 0; r < 4; ++r) {
                    const int row = mgrp * 64 + mf * 16 + (lane >> 4) * 4 + r;
                    ybuf[row * Y2LD + n] = f2bf(celu_f(acc2[mf][t][r] + bv));
                }
            }
        }
    }
    __syncthreads();

    // ---- L3: 96 -> 1 (fp32 vector; red in xbuf) ----
    {
        float* red = (float*)xbuf;
        const int m = tid & (NMOL - 1);
        const int q = tid >> 7;       // 0..3, 24 inputs each
        float accv = 0.f;
        #pragma unroll
        for (int ii = 0; ii < 24; ++ii) {
            const int i = q * 24 + ii;
            accv = fmaf(w3s[i], bf2f(ybuf[m * Y2LD + i]), accv);
        }
        red[q * NMOL + m] = accv;
        __syncthreads();
        if (tid < NMOL) {
            const float sm = red[tid] + red[NMOL + tid] + red[2 * NMOL + tid]
                           + red[3 * NMOL + tid] + bb3;
            partial[(size_t)a * NMOL + tid] = sm;
        }
    }
}

__global__ __launch_bounds__(256) void reduce_kernel(
    const float* __restrict__ partial, float* __restrict__ out)
{
    __shared__ float red[256];
    const int m = blockIdx.x;       // molecule
    const int t = threadIdx.x;
    float sv = partial[(size_t)t * NMOL + m] + partial[(size_t)(t + 256) * NMOL + m];
    red[t] = sv;
    __syncthreads();
    #pragma unroll
    for (int w = 128; w > 0; w >>= 1) {
        if (t < w) red[t] += red[t + w];
        __syncthreads();
    }
    if (t == 0) out[m] = red[0];
}

extern "C" void kernel_launch(void* const* d_in, const int* in_sizes, int n_in,
                              void* d_out, int out_size, void* d_ws, size_t ws_size,
                              hipStream_t stream) {
    const float* aev     = (const float*)d_in[0];
    const int*   species = (const int*)  d_in[1];
    const float* W0 = (const float*)d_in[2];
    const float* b0 = (const float*)d_in[3];
    const float* W1 = (const float*)d_in[4];
    const float* b1 = (const float*)d_in[5];
    const float* W2 = (const float*)d_in[6];
    const float* b2 = (const float*)d_in[7];
    const float* W3 = (const float*)d_in[8];
    const float* b3 = (const float*)d_in[9];
    float* out     = (float*)d_out;
    float* partial = (float*)d_ws;                               // 256 KiB
    ushort* Wp     = (ushort*)((char*)d_ws + WP_BYTE_OFF);       // ~0.75 MiB

    prep_kernel<<<184, 256, 0, stream>>>(W0, W1, W2, Wp);
    ani_mfma_kernel<<<NATOM, 512, 0, stream>>>(aev, species, Wp,
                                               b0, b1, b2, W3, b3, partial);
    reduce_kernel<<<NMOL, 256, 0, stream>>>(partial, out);
}

// Round 9
// 42.968 us; speedup vs baseline: 1.7628x; 1.0373x over previous
//
#include <hip/hip_runtime.h>

// ANI-1 per-species MLP, v9: v8 (M=128/block) + FORCED 128-VGPR budget via
// amdgpu_waves_per_eu(4,4). v8 evidence: compiler chose 64 VGPR (launch_bounds
// min-waves is only a floor) and spilled acc/rv in the hot loop (WRITE_SIZE
// 2.3MB scratch). LDS caps us at 2 blocks/CU = 4 waves/EU anyway, so cap max
// waves at 4 -> up to 128 VGPR, no spill.
// Pipeline: K=64 X tiles, double-buffered LDS (1 barrier/tile), rv ping-pong
// (2x4 float4), B-frags per-ks with ~50 regs free for compiler hoisting.
// Block = 512 thr (8 waves: 2 M-grp x 4 N-grp), grid = 512 atoms.
// LDS 78 KB -> 2 blocks/CU.

typedef float f32x4 __attribute__((ext_vector_type(4)));
typedef short s16x8 __attribute__((ext_vector_type(8)));

#define NMOL   128
#define NATOM  512
#define AEV    384
#define XLD    72               // K=64 tile + 8 pad
#define Y0LD   168
#define Y1LD   136
#define Y2LD   104

// Wp element offsets (bf16 units)
#define PL0    61440            // 160*384
#define PL1    20480            // 128*160
#define PL2    12288            // 96*128
#define BASE0  0
#define BASE1  245760           // 4*PL0
#define BASE2  327680           // BASE1 + 4*PL1
#define WP_BYTE_OFF 262144      // partial buffer (512*128*4) first in d_ws

__device__ __forceinline__ ushort f2bf(float f) {   // RTN-even
    uint u = __float_as_uint(f);
    return (ushort)((u + 0x7fffu + ((u >> 16) & 1u)) >> 16);
}
__device__ __forceinline__ float bf2f(ushort h) {
    return __uint_as_float(((uint)h) << 16);
}
__device__ __forceinline__ float celu_f(float v) {
    return fmaxf(v, 0.0f) + fminf(0.1f * (__expf(10.0f * v) - 1.0f), 0.0f);
}

// ---- prep: W0..W2 fp32 -> bf16 in MFMA-B-fragment order, 8 elems/thread ----
__global__ __launch_bounds__(256) void prep_kernel(
    const float* __restrict__ W0, const float* __restrict__ W1,
    const float* __restrict__ W2, ushort* __restrict__ Wp)
{
    const int idx = blockIdx.x * 256 + threadIdx.x;   // grid = 47104 (x8 elems)
    int n, k0, KS;
    size_t base;
    const float* src;
    if (idx < 30720) {                        // L0: [4][160][384], 7680 vec/species
        const int s = idx / 7680, r = idx % 7680;
        n = r / 48; k0 = (r % 48) * 8; KS = 12;
        src = W0 + (size_t)idx * 8;
        base = BASE0 + (size_t)s * PL0;
    } else if (idx < 40960) {                 // L1: [4][128][160], 2560 vec/species
        const int i2 = idx - 30720;
        const int s = i2 / 2560, r = i2 % 2560;
        n = r / 20; k0 = (r % 20) * 8; KS = 5;
        src = W1 + (size_t)i2 * 8;
        base = BASE1 + (size_t)s * PL1;
    } else {                                  // L2: [4][96][128], 1536 vec/species
        const int i2 = idx - 40960;
        const int s = i2 / 1536, r = i2 % 1536;
        n = r / 16; k0 = (r % 16) * 8; KS = 4;
        src = W2 + (size_t)i2 * 8;
        base = BASE2 + (size_t)s * PL2;
    }
    const float4 v0 = *(const float4*)(src);
    const float4 v1 = *(const float4*)(src + 4);
    const size_t fo = (size_t)((((n >> 4) * KS + (k0 >> 5)) * 64
                                + ((k0 & 31) >> 3) * 16 + (n & 15)) * 8);
    uint4 w;
    w.x = (uint)f2bf(v0.x) | ((uint)f2bf(v0.y) << 16);
    w.y = (uint)f2bf(v0.z) | ((uint)f2bf(v0.w) << 16);
    w.z = (uint)f2bf(v1.x) | ((uint)f2bf(v1.y) << 16);
    w.w = (uint)f2bf(v1.z) | ((uint)f2bf(v1.w) << 16);
    *(uint4*)(Wp + base + fo) = w;
}

__global__ __attribute__((amdgpu_flat_work_group_size(512, 512),
                          amdgpu_waves_per_eu(4, 4)))
void ani_mfma_kernel(
    const float* __restrict__ aev, const int* __restrict__ species,
    const ushort* __restrict__ Wp,
    const float* __restrict__ b0, const float* __restrict__ b1,
    const float* __restrict__ b2,
    const float* __restrict__ W3, const float* __restrict__ b3,
    float* __restrict__ partial)
{
    __shared__ __align__(16) ushort xbuf[2 * NMOL * XLD];   // 36864 B: X dbuf -> Y1 -> red
    __shared__ __align__(16) ushort ybuf[NMOL * Y0LD];      // 43008 B: Y0 -> Y2

    const int a    = blockIdx.x;        // atom
    const int tid  = threadIdx.x;
    const int lane = tid & 63;
    const int wid  = tid >> 6;
    const int mgrp = wid >> 2;          // 0..1 -> rows mgrp*64 .. +63
    const int ngrp = wid & 3;           // 0..3
    const bool has3 = (ngrp < 2);       // third N-frag (L0 nf=ngrp+8<10; L2 nf=ngrp+4<6)

    // staging map: thread covers rows mol0+32p (p=0..3), float4 col c4 of K=64 tile
    const int mol0 = tid >> 4;          // 0..31
    const int c4   = tid & 15;          // 0..15
    const size_t PSTR = (size_t)32 * NATOM * AEV;
    const float* xp = aev + ((size_t)mol0 * NATOM + a) * AEV + c4 * 4;

    const int s = species[a];
    const ushort* Bh0 = Wp + BASE0 + (size_t)s * PL0;
    const ushort* Bh1 = Wp + BASE1 + (size_t)s * PL1;
    const ushort* Bh2 = Wp + BASE2 + (size_t)s * PL2;
    const float* b0s = b0 + s * 160;
    const float* b1s = b1 + s * 128;
    const float* b2s = b2 + s * 96;
    const float* w3s = W3 + s * 96;
    const float  bb3 = b3[s];

    ushort* X0 = xbuf;
    ushort* X1 = xbuf + NMOL * XLD;

    float4 rv[2][4];                    // ping-pong prefetch (all idx const after unroll)
    auto prefetch_rv = [&](int slot, int t) {
        #pragma unroll
        for (int p = 0; p < 4; ++p)
            rv[slot][p] = *(const float4*)(xp + t * 64 + p * PSTR);
    };
    auto stage = [&](ushort* dst, int slot) {
        #pragma unroll
        for (int p = 0; p < 4; ++p) {
            uint2 ph;
            ph.x = (uint)f2bf(rv[slot][p].x) | ((uint)f2bf(rv[slot][p].y) << 16);
            ph.y = (uint)f2bf(rv[slot][p].z) | ((uint)f2bf(rv[slot][p].w) << 16);
            *(uint2*)(dst + (mol0 + 32 * p) * XLD + c4 * 4) = ph;
        }
    };

    f32x4 acc[4][3];
    const f32x4 zero = {0.f, 0.f, 0.f, 0.f};
    #pragma unroll
    for (int mf = 0; mf < 4; ++mf)
        #pragma unroll
        for (int t = 0; t < 3; ++t) acc[mf][t] = zero;

    // ---- L0: 384 -> 160, 6 K-64 tiles, dbuf, 1 barrier/tile ----
    prefetch_rv(0, 0);
    stage(X0, 0);
    prefetch_rv(1, 1);
    __syncthreads();

    #pragma unroll
    for (int t = 0; t < 6; ++t) {
        const int cur = t & 1;
        ushort* Xc = cur ? X1 : X0;
        ushort* Xn = cur ? X0 : X1;
        if (t < 4) prefetch_rv(cur, t + 2);   // HBM issue a full phase early
        #pragma unroll
        for (int ks = 0; ks < 2; ++ks) {
            const int gks = t * 2 + ks;
            const s16x8 bh0 = *(const s16x8*)(Bh0 + ((size_t)((ngrp    ) * 12 + gks) * 64 + lane) * 8);
            const s16x8 bh1 = *(const s16x8*)(Bh0 + ((size_t)((ngrp + 4) * 12 + gks) * 64 + lane) * 8);
            s16x8 bh2;
            if (has3) bh2 = *(const s16x8*)(Bh0 + ((size_t)((ngrp + 8) * 12 + gks) * 64 + lane) * 8);
            s16x8 ah[4];
            #pragma unroll
            for (int mf = 0; mf < 4; ++mf)
                ah[mf] = *(const s16x8*)(Xc + (mgrp * 64 + mf * 16 + (lane & 15)) * XLD
                                         + ks * 32 + (lane >> 4) * 8);
            #pragma unroll
            for (int mf = 0; mf < 4; ++mf) {
                acc[mf][0] = __builtin_amdgcn_mfma_f32_16x16x32_bf16(ah[mf], bh0, acc[mf][0], 0, 0, 0);
                acc[mf][1] = __builtin_amdgcn_mfma_f32_16x16x32_bf16(ah[mf], bh1, acc[mf][1], 0, 0, 0);
            }
            if (has3) {
                #pragma unroll
                for (int mf = 0; mf < 4; ++mf)
                    acc[mf][2] = __builtin_amdgcn_mfma_f32_16x16x32_bf16(ah[mf], bh2, acc[mf][2], 0, 0, 0);
            }
        }
        if (t < 5) {
            stage(Xn, cur ^ 1);       // stage tile t+1 into other buffer
            __syncthreads();
        }
    }

    // L1 B preload (issued before epilogue VALU; completes by the barrier)
    s16x8 b1r[2][5];
    #pragma unroll
    for (int ks = 0; ks < 5; ++ks) {
        b1r[0][ks] = *(const s16x8*)(Bh1 + ((size_t)((ngrp    ) * 5 + ks) * 64 + lane) * 8);
        b1r[1][ks] = *(const s16x8*)(Bh1 + ((size_t)((ngrp + 4) * 5 + ks) * 64 + lane) * 8);
    }

    // ---- L0 epilogue -> Y0 (ybuf, ld 168) ----
    #pragma unroll
    for (int t = 0; t < 3; ++t) {
        if (t < 2 || has3) {
            const int n = (ngrp + 4 * t) * 16 + (lane & 15);
            const float bv = b0s[n];
            #pragma unroll
            for (int mf = 0; mf < 4; ++mf) {
                #pragma unroll
                for (int r = 0; r < 4; ++r) {
                    const int row = mgrp * 64 + mf * 16 + (lane >> 4) * 4 + r;
                    ybuf[row * Y0LD + n] = f2bf(celu_f(acc[mf][t][r] + bv));
                }
            }
        }
    }
    __syncthreads();

    // ---- L1: 160 -> 128 (A from Y0/ybuf, C -> Y1/xbuf) ----
    f32x4 acc1[4][2];
    #pragma unroll
    for (int mf = 0; mf < 4; ++mf) { acc1[mf][0] = zero; acc1[mf][1] = zero; }
    #pragma unroll
    for (int ks = 0; ks < 5; ++ks) {
        s16x8 ah[4];
        #pragma unroll
        for (int mf = 0; mf < 4; ++mf)
            ah[mf] = *(const s16x8*)(ybuf + (mgrp * 64 + mf * 16 + (lane & 15)) * Y0LD
                                     + ks * 32 + (lane >> 4) * 8);
        #pragma unroll
        for (int mf = 0; mf < 4; ++mf) {
            acc1[mf][0] = __builtin_amdgcn_mfma_f32_16x16x32_bf16(ah[mf], b1r[0][ks], acc1[mf][0], 0, 0, 0);
            acc1[mf][1] = __builtin_amdgcn_mfma_f32_16x16x32_bf16(ah[mf], b1r[1][ks], acc1[mf][1], 0, 0, 0);
        }
    }

    // L2 B preload (completes by the post-L1-epilogue barrier)
    s16x8 b2r[2][4];
    #pragma unroll
    for (int ks = 0; ks < 4; ++ks)
        b2r[0][ks] = *(const s16x8*)(Bh2 + ((size_t)((ngrp) * 4 + ks) * 64 + lane) * 8);
    if (has3) {
        #pragma unroll
        for (int ks = 0; ks < 4; ++ks)
            b2r[1][ks] = *(const s16x8*)(Bh2 + ((size_t)((ngrp + 4) * 4 + ks) * 64 + lane) * 8);
    }

    // ---- L1 epilogue -> Y1 (xbuf, ld 136) ----
    #pragma unroll
    for (int t = 0; t < 2; ++t) {
        const int n = (ngrp + 4 * t) * 16 + (lane & 15);
        const float bv = b1s[n];
        #pragma unroll
        for (int mf = 0; mf < 4; ++mf) {
            #pragma unroll
            for (int r = 0; r < 4; ++r) {
                const int row = mgrp * 64 + mf * 16 + (lane >> 4) * 4 + r;
                xbuf[row * Y1LD + n] = f2bf(celu_f(acc1[mf][t][r] + bv));
            }
        }
    }
    __syncthreads();

    // ---- L2: 128 -> 96 (A from Y1/xbuf, C -> Y2/ybuf ld 104) ----
    f32x4 acc2[4][2];
    #pragma unroll
    for (int mf = 0; mf < 4; ++mf) { acc2[mf][0] = zero; acc2[mf][1] = zero; }
    #pragma unroll
    for (int ks = 0; ks < 4; ++ks) {
        s16x8 ah[4];
        #pragma unroll
        for (int mf = 0; mf < 4; ++mf)
            ah[mf] = *(const s16x8*)(xbuf + (mgrp * 64 + mf * 16 + (lane & 15)) * Y1LD
                                     + ks * 32 + (lane >> 4) * 8);
        #pragma unroll
        for (int mf = 0; mf < 4; ++mf) {
            acc2[mf][0] = __builtin_amdgcn_mfma_f32_16x16x32_bf16(ah[mf], b2r[0][ks], acc2[mf][0], 0, 0, 0);
            if (has3)
                acc2[mf][1] = __builtin_amdgcn_mfma_f32_16x16x32_bf16(ah[mf], b2r[1][ks], acc2[mf][1], 0, 0, 0);
        }
    }
    __syncthreads();   // xbuf (Y1) reads done; xbuf reused for red below

    // ---- L2 epilogue -> Y2 (ybuf, ld 104) ----
    #pragma unroll
    for (int t = 0; t < 2; ++t) {
        if (t == 0 || has3) {
            const int n = (ngrp + 4 * t) * 16 + (lane & 15);   // < 96
            const float bv = b2s[n];
            #pragma unroll
            for (int mf = 0; mf < 4; ++mf) {
                #pragma unroll
                for (int r = 0; r < 4; ++r) {
                    const int row = mgrp * 64 + mf * 16 + (lane >> 4) * 4 + r;
                    ybuf[row * Y2LD + n] = f2bf(celu_f(acc2[mf][t][r] + bv));
                }
            }
        }
    }
    __syncthreads();

    // ---- L3: 96 -> 1 (fp32 vector; red in xbuf) ----
    {
        float* red = (float*)xbuf;
        const int m = tid & (NMOL - 1);
        const int q = tid >> 7;       // 0..3, 24 inputs each
        float accv = 0.f;
        #pragma unroll
        for (int ii = 0; ii < 24; ++ii) {
            const int i = q * 24 + ii;
            accv = fmaf(w3s[i], bf2f(ybuf[m * Y2LD + i]), accv);
        }
        red[q * NMOL + m] = accv;
        __syncthreads();
        if (tid < NMOL) {
            const float sm = red[tid] + red[NMOL + tid] + red[2 * NMOL + tid]
                           + red[3 * NMOL + tid] + bb3;
            partial[(size_t)a * NMOL + tid] = sm;
        }
    }
}

__global__ __launch_bounds__(256) void reduce_kernel(
    const float* __restrict__ partial, float* __restrict__ out)
{
    __shared__ float red[256];
    const int m = blockIdx.x;       // molecule
    const int t = threadIdx.x;
    float sv = partial[(size_t)t * NMOL + m] + partial[(size_t)(t + 256) * NMOL + m];
    red[t] = sv;
    __syncthreads();
    #pragma unroll
    for (int w = 128; w > 0; w >>= 1) {
        if (t < w) red[t] += red[t + w];
        __syncthreads();
    }
    if (t == 0) out[m] = red[0];
}

extern "C" void kernel_launch(void* const* d_in, const int* in_sizes, int n_in,
                              void* d_out, int out_size, void* d_ws, size_t ws_size,
                              hipStream_t stream) {
    const float* aev     = (const float*)d_in[0];
    const int*   species = (const int*)  d_in[1];
    const float* W0 = (const float*)d_in[2];
    const float* b0 = (const float*)d_in[3];
    const float* W1 = (const float*)d_in[4];
    const float* b1 = (const float*)d_in[5];
    const float* W2 = (const float*)d_in[6];
    const float* b2 = (const float*)d_in[7];
    const float* W3 = (const float*)d_in[8];
    const float* b3 = (const float*)d_in[9];
    float* out     = (float*)d_out;
    float* partial = (float*)d_ws;                               // 256 KiB
    ushort* Wp     = (ushort*)((char*)d_ws + WP_BYTE_OFF);       // ~0.75 MiB

    prep_kernel<<<184, 256, 0, stream>>>(W0, W1, W2, Wp);
    ani_mfma_kernel<<<NATOM, 512, 0, stream>>>(aev, species, Wp,
                                               b0, b1, b2, W3, b3, partial);
    reduce_kernel<<<NMOL, 256, 0, stream>>>(partial, out);
}